// Round 2
// baseline (380.516 us; speedup 1.0000x reference)
//
#include <hip/hip_runtime.h>

#define NTOK 2304   // 48*48 tokens
#define NH 12
#define HD 64

typedef __attribute__((ext_vector_type(8))) short bf16x8;
typedef __attribute__((ext_vector_type(4))) float f32x4;

__device__ __forceinline__ unsigned short f2bf(float f){
  union { float f; unsigned u; } v; v.f = f;
  unsigned r = v.u + 0x7fffu + ((v.u >> 16) & 1u);
  return (unsigned short)(r >> 16);
}
__device__ __forceinline__ float bf2f(unsigned short h){
  union { unsigned u; float f; } v; v.u = ((unsigned)h) << 16;
  return v.f;
}
__device__ __forceinline__ void gload_lds16(const void* g, void* lds){
  __builtin_amdgcn_global_load_lds(
    (const __attribute__((address_space(1))) unsigned int*)g,
    (__attribute__((address_space(3))) unsigned int*)lds, 16, 0, 0);
}

// ---------------- fp32 -> bf16 convert ----------------
__global__ __launch_bounds__(256) void cvt_f32_bf16(const float* __restrict__ src,
                                                    unsigned short* __restrict__ dst, int n4){
  int i = blockIdx.x * 256 + threadIdx.x;
  if (i >= n4) return;
  float4 v = ((const float4*)src)[i];
  union { unsigned short u[4]; unsigned long long ll; } o;
  o.u[0] = f2bf(v.x); o.u[1] = f2bf(v.y); o.u[2] = f2bf(v.z); o.u[3] = f2bf(v.w);
  ((unsigned long long*)dst)[i] = o.ll;
}

// ---------------- LoRA t = x @ A^T  (t[3][2304][4]) ----------------
__global__ __launch_bounds__(256) void lora_t_kernel(const float* __restrict__ x,
    const float* __restrict__ Aq, const float* __restrict__ Ak, const float* __restrict__ Av,
    float* __restrict__ t){
  int wave = (blockIdx.x * 256 + threadIdx.x) >> 6;   // token
  int lane = threadIdx.x & 63;
  if (wave >= NTOK) return;
  const float* xr = x + (size_t)wave * 768;
  float part[12];
  #pragma unroll
  for (int j = 0; j < 12; j++) part[j] = 0.f;
  for (int k = lane; k < 768; k += 64){
    float xv = xr[k];
    #pragma unroll
    for (int r = 0; r < 4; r++){
      part[r]     += xv * Aq[r*768 + k];
      part[4 + r] += xv * Ak[r*768 + k];
      part[8 + r] += xv * Av[r*768 + k];
    }
  }
  #pragma unroll
  for (int j = 0; j < 12; j++){
    float v = part[j];
    #pragma unroll
    for (int off = 32; off; off >>= 1) v += __shfl_xor(v, off);
    if (lane == 0){
      int mat = j >> 2, r = j & 3;
      t[((size_t)mat * NTOK + wave) * 4 + r] = v;
    }
  }
}

// ---------------- fused qkv GEMM (+bias +LoRA, writes q(scaled),k,vT) ----------------
__global__ __launch_bounds__(256) void qkv_gemm(
    const unsigned short* __restrict__ xg,   // [2304][768] bf16
    const unsigned short* __restrict__ wg,   // [2304][768] bf16
    const float* __restrict__ bias,          // [2304]
    const float* __restrict__ t,             // [3][2304][4]
    const float* __restrict__ Bq, const float* __restrict__ Bk, const float* __restrict__ Bv, // [768][4]
    unsigned short* __restrict__ qo,         // [12][2304][64]  (pre-scaled by 0.125)
    unsigned short* __restrict__ ko,         // [12][2304][64]
    unsigned short* __restrict__ vT)         // [12][64][2304]
{
  __shared__ short As[128*64];
  __shared__ short Bs[128*64];
  const int tid = threadIdx.x;
  const int lane = tid & 63;
  const int wv = tid >> 6;
  const int r = lane & 15, g = lane >> 4;
  const int wm = (wv >> 1) * 64, wn = (wv & 1) * 64;
  const int m0 = blockIdx.y * 128, n0 = blockIdx.x * 128;

  f32x4 acc[4][4];
  #pragma unroll
  for (int i = 0; i < 4; i++)
    #pragma unroll
    for (int j = 0; j < 4; j++) acc[i][j] = (f32x4){0.f, 0.f, 0.f, 0.f};

  for (int k0 = 0; k0 < 768; k0 += 64){
    __syncthreads();
    #pragma unroll
    for (int it = 0; it < 4; it++){
      int f = it * 256 + tid;
      int row = f >> 3, u = f & 7;
      int us = ((u ^ (row & 7)) << 3);
      gload_lds16(xg + (size_t)(m0 + row) * 768 + k0 + us, &As[f * 8]);
      gload_lds16(wg + (size_t)(n0 + row) * 768 + k0 + us, &Bs[f * 8]);
    }
    __syncthreads();
    #pragma unroll
    for (int ks = 0; ks < 2; ks++){
      bf16x8 af[4], bfr[4];
      #pragma unroll
      for (int mt = 0; mt < 4; mt++){
        int row = wm + mt * 16 + r;
        af[mt] = *(const bf16x8*)&As[row * 64 + ((((ks << 2) | g) ^ (r & 7)) << 3)];
      }
      #pragma unroll
      for (int nt = 0; nt < 4; nt++){
        int row = wn + nt * 16 + r;
        bfr[nt] = *(const bf16x8*)&Bs[row * 64 + ((((ks << 2) | g) ^ (r & 7)) << 3)];
      }
      #pragma unroll
      for (int mt = 0; mt < 4; mt++)
        #pragma unroll
        for (int nt = 0; nt < 4; nt++)
          acc[mt][nt] = __builtin_amdgcn_mfma_f32_16x16x32_bf16(af[mt], bfr[nt], acc[mt][nt], 0, 0, 0);
    }
  }

  const int part = n0 / 768;
  const float* Bl = (part == 0) ? Bq : ((part == 1) ? Bk : Bv);
  const float* tp = t + (size_t)part * NTOK * 4;
  #pragma unroll
  for (int mt = 0; mt < 4; mt++){
    #pragma unroll
    for (int reg = 0; reg < 4; reg++){
      int row_m = m0 + wm + mt * 16 + g * 4 + reg;
      float4 tv = *(const float4*)&tp[row_m * 4];
      #pragma unroll
      for (int nt = 0; nt < 4; nt++){
        int col = n0 + wn + nt * 16 + r;
        int cc = col - part * 768;
        float4 bw = *(const float4*)&Bl[cc * 4];
        float val = acc[mt][nt][reg] + bias[col]
                  + 0.25f * (tv.x * bw.x + tv.y * bw.y + tv.z * bw.z + tv.w * bw.w);
        int head = cc >> 6, d = cc & 63;
        if (part == 0)      qo[((size_t)head * NTOK + row_m) * 64 + d] = f2bf(val * 0.125f);
        else if (part == 1) ko[((size_t)head * NTOK + row_m) * 64 + d] = f2bf(val);
        else                vT[((size_t)head * 64 + d) * NTOK + row_m] = f2bf(val);
      }
    }
  }
}

// ---------------- rel_h / rel_w precompute ----------------
__global__ __launch_bounds__(256) void rel_kernel(
    const unsigned short* __restrict__ qg, const float* __restrict__ rph, const float* __restrict__ rpw,
    float* __restrict__ rel_h, float* __restrict__ rel_w){
  int ih = blockIdx.x, head = blockIdx.y;
  __shared__ float qs[48 * 64];
  __shared__ float hs[48 * 64];
  __shared__ float wsm[95 * 64];
  for (int idx = threadIdx.x; idx < 48 * 64; idx += 256){
    qs[idx] = bf2f(qg[((size_t)head * NTOK + ih * 48) * 64 + idx]);
    hs[idx] = rph[ih * 64 + idx];
  }
  for (int idx = threadIdx.x; idx < 95 * 64; idx += 256) wsm[idx] = rpw[idx];
  __syncthreads();
  for (int idx = threadIdx.x; idx < 48 * 96; idx += 256){
    int w = idx / 96, c = idx % 96;
    const float4* q4 = (const float4*)&qs[w * 64];
    const float4* r4 = (c < 48) ? (const float4*)&hs[(47 - c) * 64]
                                : (const float4*)&wsm[(w - (c - 48) + 47) * 64];
    float s = 0.f;
    #pragma unroll
    for (int d = 0; d < 16; d++){
      float4 a = q4[d], b = r4[d];
      s += a.x * b.x + a.y * b.y + a.z * b.z + a.w * b.w;
    }
    s *= 8.f;  // undo q pre-scale
    int gi = head * NTOK + ih * 48 + w;
    if (c < 48) rel_h[(size_t)gi * 48 + c] = s;
    else        rel_w[(size_t)gi * 48 + (c - 48)] = s;
  }
}

// ---------------- flash attention: 32 q-rows/block, 4 waves split KV ----------------
__global__ __launch_bounds__(256, 4) void attn_kernel(
    const unsigned short* __restrict__ qg,   // [12][2304][64] scaled
    const unsigned short* __restrict__ kg,   // [12][2304][64]
    const unsigned short* __restrict__ vT,   // [12][64][2304]
    const float* __restrict__ rel_h,         // [12][2304][48]
    const float* __restrict__ rel_w,         // [12][2304][48]
    unsigned short* __restrict__ ao)         // [2304][768]
{
  // LDS: phase1 {rel_s 12KB | P_lds 16KB}  phase2 {Obuf 32KB (aliases phase1)} + msh/lsh/Lsh
  __shared__ __align__(16) char smem[32768 + 1152];
  float* rel_s = (float*)smem;                              // [32][96]
  unsigned short* P_lds = (unsigned short*)(smem + 12288);  // [4][32][64]
  float* Obuf = (float*)smem;                               // [4][32][64]
  float* msh = (float*)(smem + 32768);                      // [4][32]
  float* lsh = (float*)(smem + 32768 + 512);                // [4][32]
  float* Lsh = (float*)(smem + 32768 + 1024);               // [32]

  const int head = blockIdx.y;
  const int q0 = blockIdx.x * 32;
  const int tid = threadIdx.x, lane = tid & 63, wv = tid >> 6;
  const int r = lane & 15, g = lane >> 4;

  for (int idx = tid; idx < 32 * 96; idx += 256){
    int i = idx / 96, c = idx % 96;
    int token = head * NTOK + q0 + i;
    rel_s[idx] = (c < 48) ? rel_h[(size_t)token * 48 + c] : rel_w[(size_t)token * 48 + (c - 48)];
  }
  __syncthreads();

  bf16x8 qf[2][2];
  #pragma unroll
  for (int mt = 0; mt < 2; mt++)
    #pragma unroll
    for (int ks = 0; ks < 2; ks++)
      qf[mt][ks] = *(const bf16x8*)&qg[((size_t)head * NTOK + q0 + mt * 16 + r) * 64 + ks * 32 + g * 8];

  f32x4 Oa[2][4];
  float mrun[2][4], lrun[2][4];
  #pragma unroll
  for (int mt = 0; mt < 2; mt++){
    #pragma unroll
    for (int dt = 0; dt < 4; dt++) Oa[mt][dt] = (f32x4){0.f, 0.f, 0.f, 0.f};
    #pragma unroll
    for (int reg = 0; reg < 4; reg++){ mrun[mt][reg] = -1e30f; lrun[mt][reg] = 0.f; }
  }

  unsigned short* pbase = &P_lds[wv * 32 * 64];

  // each wave handles 9 of 36 k-tiles
  for (int it = 0; it < 9; it++){
    int key0 = (wv * 9 + it) * 64;
    bf16x8 kf[4][2];
    #pragma unroll
    for (int nt = 0; nt < 4; nt++)
      #pragma unroll
      for (int ks = 0; ks < 2; ks++)
        kf[nt][ks] = *(const bf16x8*)&kg[((size_t)head * NTOK + key0 + nt * 16 + r) * 64 + ks * 32 + g * 8];

    f32x4 s[2][4];
    #pragma unroll
    for (int mt = 0; mt < 2; mt++)
      #pragma unroll
      for (int nt = 0; nt < 4; nt++) s[mt][nt] = (f32x4){0.f, 0.f, 0.f, 0.f};
    #pragma unroll
    for (int mt = 0; mt < 2; mt++)
      #pragma unroll
      for (int nt = 0; nt < 4; nt++){
        s[mt][nt] = __builtin_amdgcn_mfma_f32_16x16x32_bf16(qf[mt][0], kf[nt][0], s[mt][nt], 0, 0, 0);
        s[mt][nt] = __builtin_amdgcn_mfma_f32_16x16x32_bf16(qf[mt][1], kf[nt][1], s[mt][nt], 0, 0, 0);
      }

    int kh[4], kw[4];
    #pragma unroll
    for (int nt = 0; nt < 4; nt++){
      int key = key0 + nt * 16 + r;
      kh[nt] = key / 48; kw[nt] = key % 48;
    }
    #pragma unroll
    for (int mt = 0; mt < 2; mt++)
      #pragma unroll
      for (int reg = 0; reg < 4; reg++){
        const float* rs = &rel_s[(mt * 16 + g * 4 + reg) * 96];
        #pragma unroll
        for (int nt = 0; nt < 4; nt++)
          s[mt][nt][reg] += rs[kh[nt]] + rs[48 + kw[nt]];
      }

    // online softmax (per-wave partial)
    #pragma unroll
    for (int mt = 0; mt < 2; mt++)
      #pragma unroll
      for (int reg = 0; reg < 4; reg++){
        float tm = fmaxf(fmaxf(s[mt][0][reg], s[mt][1][reg]), fmaxf(s[mt][2][reg], s[mt][3][reg]));
        tm = fmaxf(tm, __shfl_xor(tm, 1));
        tm = fmaxf(tm, __shfl_xor(tm, 2));
        tm = fmaxf(tm, __shfl_xor(tm, 4));
        tm = fmaxf(tm, __shfl_xor(tm, 8));
        float mold = mrun[mt][reg];
        float mnew = fmaxf(mold, tm);
        float alpha = __expf(mold - mnew);
        mrun[mt][reg] = mnew;
        float ps = 0.f;
        #pragma unroll
        for (int nt = 0; nt < 4; nt++){
          float p = __expf(s[mt][nt][reg] - mnew);
          s[mt][nt][reg] = p;
          ps += p;
        }
        ps += __shfl_xor(ps, 1);
        ps += __shfl_xor(ps, 2);
        ps += __shfl_xor(ps, 4);
        ps += __shfl_xor(ps, 8);
        lrun[mt][reg] = lrun[mt][reg] * alpha + ps;
        #pragma unroll
        for (int dt = 0; dt < 4; dt++) Oa[mt][dt][reg] *= alpha;
      }

    // P -> per-wave LDS (swizzled), D-layout write
    #pragma unroll
    for (int mt = 0; mt < 2; mt++)
      #pragma unroll
      for (int reg = 0; reg < 4; reg++){
        int prow = mt * 16 + g * 4 + reg;
        #pragma unroll
        for (int nt = 0; nt < 4; nt++){
          int pcol = nt * 16 + r;
          pbase[prow * 64 + ((((pcol >> 3) ^ (prow & 7)) << 3) | (pcol & 7))] = f2bf(s[mt][nt][reg]);
        }
      }

    // P A-frag read (swizzled) + PV
    bf16x8 pf[2][2];
    #pragma unroll
    for (int mt = 0; mt < 2; mt++)
      #pragma unroll
      for (int ks = 0; ks < 2; ks++){
        int prow = mt * 16 + r;
        pf[mt][ks] = *(const bf16x8*)&pbase[prow * 64 + ((((ks << 2) | g) ^ (prow & 7)) << 3)];
      }
    #pragma unroll
    for (int dt = 0; dt < 4; dt++)
      #pragma unroll
      for (int ks = 0; ks < 2; ks++){
        bf16x8 vf = *(const bf16x8*)&vT[((size_t)head * 64 + dt * 16 + r) * NTOK + key0 + ks * 32 + g * 8];
        #pragma unroll
        for (int mt = 0; mt < 2; mt++)
          Oa[mt][dt] = __builtin_amdgcn_mfma_f32_16x16x32_bf16(pf[mt][ks], vf, Oa[mt][dt], 0, 0, 0);
      }
  }

  // ---- cross-wave flash combine ----
  __syncthreads();   // all waves done with rel_s / P_lds
  if (r == 0){
    #pragma unroll
    for (int mt = 0; mt < 2; mt++)
      #pragma unroll
      for (int reg = 0; reg < 4; reg++){
        int row = mt * 16 + g * 4 + reg;
        msh[wv * 32 + row] = mrun[mt][reg];
        lsh[wv * 32 + row] = lrun[mt][reg];
      }
  }
  __syncthreads();
  #pragma unroll
  for (int mt = 0; mt < 2; mt++)
    #pragma unroll
    for (int reg = 0; reg < 4; reg++){
      int row = mt * 16 + g * 4 + reg;
      float m0v = msh[row], m1 = msh[32 + row], m2 = msh[64 + row], m3 = msh[96 + row];
      float M = fmaxf(fmaxf(m0v, m1), fmaxf(m2, m3));
      float L = lsh[row]      * __expf(m0v - M) + lsh[32 + row] * __expf(m1 - M)
              + lsh[64 + row] * __expf(m2 - M)  + lsh[96 + row] * __expf(m3 - M);
      float al = __expf(mrun[mt][reg] - M);
      if (wv == 0 && r == 0) Lsh[row] = L;
      #pragma unroll
      for (int dt = 0; dt < 4; dt++)
        Obuf[(wv * 32 + row) * 64 + dt * 16 + r] = Oa[mt][dt][reg] * al;
    }
  __syncthreads();
  {
    int row = tid >> 3;
    int dbase = (tid & 7) * 8;
    float sum[8];
    #pragma unroll
    for (int j = 0; j < 8; j++) sum[j] = 0.f;
    #pragma unroll
    for (int w4 = 0; w4 < 4; w4++){
      const float4* p = (const float4*)&Obuf[(w4 * 32 + row) * 64 + dbase];
      float4 a = p[0], b = p[1];
      sum[0] += a.x; sum[1] += a.y; sum[2] += a.z; sum[3] += a.w;
      sum[4] += b.x; sum[5] += b.y; sum[6] += b.z; sum[7] += b.w;
    }
    float invL = 1.f / Lsh[row];
    union { unsigned short u[8]; bf16x8 v; } o;
    #pragma unroll
    for (int j = 0; j < 8; j++) o.u[j] = f2bf(sum[j] * invL);
    int token = q0 + row;
    *(bf16x8*)&ao[(size_t)token * 768 + head * 64 + dbase] = o.v;
  }
}

// ---------------- proj GEMM ----------------
__global__ __launch_bounds__(256) void proj_gemm(
    const unsigned short* __restrict__ ag,   // [2304][768] bf16
    const unsigned short* __restrict__ wg,   // [768][768] bf16
    const float* __restrict__ bias,
    float* __restrict__ out)
{
  __shared__ short As[128*64];
  __shared__ short Bs[128*64];
  const int tid = threadIdx.x;
  const int lane = tid & 63;
  const int wv = tid >> 6;
  const int r = lane & 15, g = lane >> 4;
  const int wm = (wv >> 1) * 64, wn = (wv & 1) * 64;
  const int m0 = blockIdx.y * 128, n0 = blockIdx.x * 128;

  f32x4 acc[4][4];
  #pragma unroll
  for (int i = 0; i < 4; i++)
    #pragma unroll
    for (int j = 0; j < 4; j++) acc[i][j] = (f32x4){0.f, 0.f, 0.f, 0.f};

  for (int k0 = 0; k0 < 768; k0 += 64){
    __syncthreads();
    #pragma unroll
    for (int it = 0; it < 4; it++){
      int f = it * 256 + tid;
      int row = f >> 3, u = f & 7;
      int us = ((u ^ (row & 7)) << 3);
      gload_lds16(ag + (size_t)(m0 + row) * 768 + k0 + us, &As[f * 8]);
      gload_lds16(wg + (size_t)(n0 + row) * 768 + k0 + us, &Bs[f * 8]);
    }
    __syncthreads();
    #pragma unroll
    for (int ks = 0; ks < 2; ks++){
      bf16x8 af[4], bfr[4];
      #pragma unroll
      for (int mt = 0; mt < 4; mt++){
        int row = wm + mt * 16 + r;
        af[mt] = *(const bf16x8*)&As[row * 64 + ((((ks << 2) | g) ^ (r & 7)) << 3)];
      }
      #pragma unroll
      for (int nt = 0; nt < 4; nt++){
        int row = wn + nt * 16 + r;
        bfr[nt] = *(const bf16x8*)&Bs[row * 64 + ((((ks << 2) | g) ^ (r & 7)) << 3)];
      }
      #pragma unroll
      for (int mt = 0; mt < 4; mt++)
        #pragma unroll
        for (int nt = 0; nt < 4; nt++)
          acc[mt][nt] = __builtin_amdgcn_mfma_f32_16x16x32_bf16(af[mt], bfr[nt], acc[mt][nt], 0, 0, 0);
    }
  }

  #pragma unroll
  for (int mt = 0; mt < 4; mt++)
    #pragma unroll
    for (int reg = 0; reg < 4; reg++){
      int row_m = m0 + wm + mt * 16 + g * 4 + reg;
      #pragma unroll
      for (int nt = 0; nt < 4; nt++){
        int col = n0 + wn + nt * 16 + r;
        out[(size_t)row_m * 768 + col] = acc[mt][nt][reg] + bias[col];
      }
    }
}

extern "C" void kernel_launch(void* const* d_in, const int* in_sizes, int n_in,
                              void* d_out, int out_size, void* d_ws, size_t ws_size,
                              hipStream_t stream){
  (void)in_sizes; (void)n_in; (void)out_size; (void)ws_size;
  const float* x      = (const float*)d_in[0];
  const float* qkv_w  = (const float*)d_in[1];
  const float* qkv_b  = (const float*)d_in[2];
  const float* proj_w = (const float*)d_in[3];
  const float* proj_b = (const float*)d_in[4];
  const float* rph    = (const float*)d_in[5];
  const float* rpw    = (const float*)d_in[6];
  const float* Aq     = (const float*)d_in[7];
  const float* Bq     = (const float*)d_in[8];
  const float* Ak     = (const float*)d_in[9];
  const float* Bk     = (const float*)d_in[10];
  const float* Av     = (const float*)d_in[11];
  const float* Bv     = (const float*)d_in[12];

  char* w = (char*)d_ws;
  unsigned short* xb  = (unsigned short*)(w + 0);         // 2304*768 bf16
  unsigned short* wqb = (unsigned short*)(w + 3538944);   // 2304*768 bf16
  unsigned short* wpb = (unsigned short*)(w + 7077888);   //  768*768 bf16
  unsigned short* qb  = (unsigned short*)(w + 8257536);   // 12*2304*64 bf16 (scaled)
  unsigned short* kb  = (unsigned short*)(w + 11796480);  // 12*2304*64 bf16
  unsigned short* vtb = (unsigned short*)(w + 15335424);  // 12*64*2304 bf16
  float* tb           = (float*)(w + 18874368);           // 3*2304*4 f32
  float* rhb          = (float*)(w + 18984960);           // 12*2304*48 f32
  float* rwb          = (float*)(w + 24293376);           // 12*2304*48 f32
  unsigned short* aob = (unsigned short*)(w + 29601792);  // 2304*768 bf16

  cvt_f32_bf16<<<1728, 256, 0, stream>>>(x, xb, 442368);
  cvt_f32_bf16<<<1728, 256, 0, stream>>>(qkv_w, wqb, 442368);
  cvt_f32_bf16<<<576, 256, 0, stream>>>(proj_w, wpb, 147456);
  lora_t_kernel<<<576, 256, 0, stream>>>(x, Aq, Ak, Av, tb);
  qkv_gemm<<<dim3(18, 18), 256, 0, stream>>>(xb, wqb, qkv_b, tb, Bq, Bk, Bv, qb, kb, vtb);
  rel_kernel<<<dim3(48, 12), 256, 0, stream>>>(qb, rph, rpw, rhb, rwb);
  attn_kernel<<<dim3(72, 12), 256, 0, stream>>>(qb, kb, vtb, rhb, rwb, aob);
  proj_gemm<<<dim3(6, 18), 256, 0, stream>>>(aob, wpb, proj_b, (float*)d_out);
}

// Round 3
// 269.949 us; speedup vs baseline: 1.4096x; 1.4096x over previous
//
#include <hip/hip_runtime.h>

#define NTOK 2304   // 48*48 tokens
#define NH 12
#define HD 64

typedef __attribute__((ext_vector_type(8))) short bf16x8;
typedef __attribute__((ext_vector_type(4))) float f32x4;

__device__ __forceinline__ unsigned short f2bf(float f){
  union { float f; unsigned u; } v; v.f = f;
  unsigned r = v.u + 0x7fffu + ((v.u >> 16) & 1u);
  return (unsigned short)(r >> 16);
}
__device__ __forceinline__ float bf2f(unsigned short h){
  union { unsigned u; float f; } v; v.u = ((unsigned)h) << 16;
  return v.f;
}
__device__ __forceinline__ void gload_lds16(const void* g, void* lds){
  __builtin_amdgcn_global_load_lds(
    (const __attribute__((address_space(1))) unsigned int*)g,
    (__attribute__((address_space(3))) unsigned int*)lds, 16, 0, 0);
}

// ---------------- fp32 -> bf16 convert ----------------
__global__ __launch_bounds__(256) void cvt_f32_bf16(const float* __restrict__ src,
                                                    unsigned short* __restrict__ dst, int n4){
  int i = blockIdx.x * 256 + threadIdx.x;
  if (i >= n4) return;
  float4 v = ((const float4*)src)[i];
  union { unsigned short u[4]; unsigned long long ll; } o;
  o.u[0] = f2bf(v.x); o.u[1] = f2bf(v.y); o.u[2] = f2bf(v.z); o.u[3] = f2bf(v.w);
  ((unsigned long long*)dst)[i] = o.ll;
}

// ---------------- LoRA t = x @ A^T  (t[3][2304][4]) ----------------
__global__ __launch_bounds__(256) void lora_t_kernel(const float* __restrict__ x,
    const float* __restrict__ Aq, const float* __restrict__ Ak, const float* __restrict__ Av,
    float* __restrict__ t){
  int wave = (blockIdx.x * 256 + threadIdx.x) >> 6;   // token
  int lane = threadIdx.x & 63;
  if (wave >= NTOK) return;
  const float* xr = x + (size_t)wave * 768;
  float part[12];
  #pragma unroll
  for (int j = 0; j < 12; j++) part[j] = 0.f;
  for (int k = lane; k < 768; k += 64){
    float xv = xr[k];
    #pragma unroll
    for (int r = 0; r < 4; r++){
      part[r]     += xv * Aq[r*768 + k];
      part[4 + r] += xv * Ak[r*768 + k];
      part[8 + r] += xv * Av[r*768 + k];
    }
  }
  #pragma unroll
  for (int j = 0; j < 12; j++){
    float v = part[j];
    #pragma unroll
    for (int off = 32; off; off >>= 1) v += __shfl_xor(v, off);
    if (lane == 0){
      int mat = j >> 2, r = j & 3;
      t[((size_t)mat * NTOK + wave) * 4 + r] = v;
    }
  }
}

// ---------------- fused qkv GEMM (+bias +LoRA, writes q(scaled),k,vT) ----------------
__global__ __launch_bounds__(256) void qkv_gemm(
    const unsigned short* __restrict__ xg,   // [2304][768] bf16
    const unsigned short* __restrict__ wg,   // [2304][768] bf16
    const float* __restrict__ bias,          // [2304]
    const float* __restrict__ t,             // [3][2304][4]
    const float* __restrict__ Bq, const float* __restrict__ Bk, const float* __restrict__ Bv, // [768][4]
    unsigned short* __restrict__ qo,         // [12][2304][64]  (pre-scaled by 0.125)
    unsigned short* __restrict__ ko,         // [12][2304][64]
    unsigned short* __restrict__ vT)         // [12][64][2304]
{
  __shared__ short As[128*64];
  __shared__ short Bs[128*64];
  const int tid = threadIdx.x;
  const int lane = tid & 63;
  const int wv = tid >> 6;
  const int r = lane & 15, g = lane >> 4;
  const int wm = (wv >> 1) * 64, wn = (wv & 1) * 64;
  const int m0 = blockIdx.y * 128, n0 = blockIdx.x * 128;

  f32x4 acc[4][4];
  #pragma unroll
  for (int i = 0; i < 4; i++)
    #pragma unroll
    for (int j = 0; j < 4; j++) acc[i][j] = (f32x4){0.f, 0.f, 0.f, 0.f};

  for (int k0 = 0; k0 < 768; k0 += 64){
    __syncthreads();
    #pragma unroll
    for (int it = 0; it < 4; it++){
      int f = it * 256 + tid;
      int row = f >> 3, u = f & 7;
      int us = ((u ^ (row & 7)) << 3);
      gload_lds16(xg + (size_t)(m0 + row) * 768 + k0 + us, &As[f * 8]);
      gload_lds16(wg + (size_t)(n0 + row) * 768 + k0 + us, &Bs[f * 8]);
    }
    __syncthreads();
    #pragma unroll
    for (int ks = 0; ks < 2; ks++){
      bf16x8 af[4], bfr[4];
      #pragma unroll
      for (int mt = 0; mt < 4; mt++){
        int row = wm + mt * 16 + r;
        af[mt] = *(const bf16x8*)&As[row * 64 + ((((ks << 2) | g) ^ (r & 7)) << 3)];
      }
      #pragma unroll
      for (int nt = 0; nt < 4; nt++){
        int row = wn + nt * 16 + r;
        bfr[nt] = *(const bf16x8*)&Bs[row * 64 + ((((ks << 2) | g) ^ (r & 7)) << 3)];
      }
      #pragma unroll
      for (int mt = 0; mt < 4; mt++)
        #pragma unroll
        for (int nt = 0; nt < 4; nt++)
          acc[mt][nt] = __builtin_amdgcn_mfma_f32_16x16x32_bf16(af[mt], bfr[nt], acc[mt][nt], 0, 0, 0);
    }
  }

  const int part = n0 / 768;
  const float* Bl = (part == 0) ? Bq : ((part == 1) ? Bk : Bv);
  const float* tp = t + (size_t)part * NTOK * 4;
  #pragma unroll
  for (int mt = 0; mt < 4; mt++){
    #pragma unroll
    for (int reg = 0; reg < 4; reg++){
      int row_m = m0 + wm + mt * 16 + g * 4 + reg;
      float4 tv = *(const float4*)&tp[row_m * 4];
      #pragma unroll
      for (int nt = 0; nt < 4; nt++){
        int col = n0 + wn + nt * 16 + r;
        int cc = col - part * 768;
        float4 bw = *(const float4*)&Bl[cc * 4];
        float val = acc[mt][nt][reg] + bias[col]
                  + 0.25f * (tv.x * bw.x + tv.y * bw.y + tv.z * bw.z + tv.w * bw.w);
        int head = cc >> 6, d = cc & 63;
        if (part == 0)      qo[((size_t)head * NTOK + row_m) * 64 + d] = f2bf(val * 0.125f);
        else if (part == 1) ko[((size_t)head * NTOK + row_m) * 64 + d] = f2bf(val);
        else                vT[((size_t)head * 64 + d) * NTOK + row_m] = f2bf(val);
      }
    }
  }
}

// ---------------- rel_h / rel_w precompute ----------------
__global__ __launch_bounds__(256) void rel_kernel(
    const unsigned short* __restrict__ qg, const float* __restrict__ rph, const float* __restrict__ rpw,
    float* __restrict__ rel_h, float* __restrict__ rel_w){
  int ih = blockIdx.x, head = blockIdx.y;
  __shared__ float qs[48 * 64];
  __shared__ float hs[48 * 64];
  __shared__ float wsm[95 * 64];
  for (int idx = threadIdx.x; idx < 48 * 64; idx += 256){
    qs[idx] = bf2f(qg[((size_t)head * NTOK + ih * 48) * 64 + idx]);
    hs[idx] = rph[ih * 64 + idx];
  }
  for (int idx = threadIdx.x; idx < 95 * 64; idx += 256) wsm[idx] = rpw[idx];
  __syncthreads();
  for (int idx = threadIdx.x; idx < 48 * 96; idx += 256){
    int w = idx / 96, c = idx % 96;
    const float4* q4 = (const float4*)&qs[w * 64];
    const float4* r4 = (c < 48) ? (const float4*)&hs[(47 - c) * 64]
                                : (const float4*)&wsm[(w - (c - 48) + 47) * 64];
    float s = 0.f;
    #pragma unroll
    for (int d = 0; d < 16; d++){
      float4 a = q4[d], b = r4[d];
      s += a.x * b.x + a.y * b.y + a.z * b.z + a.w * b.w;
    }
    s *= 8.f;  // undo q pre-scale
    int gi = head * NTOK + ih * 48 + w;
    if (c < 48) rel_h[(size_t)gi * 48 + c] = s;
    else        rel_w[(size_t)gi * 48 + (c - 48)] = s;
  }
}

// ---------------- flash attention: 32 q-rows/block, 4 waves split KV ----------------
// v3: register-level software pipeline (K double-buffer, V hoisted-early),
//     padded LDS strides (rel_s 100 f32, P_lds 72 u16) to kill bank conflicts.
__global__ __launch_bounds__(256, 2) void attn_kernel(
    const unsigned short* __restrict__ qg,   // [12][2304][64] scaled
    const unsigned short* __restrict__ kg,   // [12][2304][64]
    const unsigned short* __restrict__ vT,   // [12][64][2304]
    const float* __restrict__ rel_h,         // [12][2304][48]
    const float* __restrict__ rel_w,         // [12][2304][48]
    unsigned short* __restrict__ ao)         // [2304][768]
{
  // phase1: rel_s [32][100] f32 (12800B) | P_lds [4][32][72] u16 (18432B)
  // phase2: Obuf [4][32][64] f32 (32768B, aliases phase1)
  __shared__ __align__(16) char smem[32768 + 1152];
  float* rel_s = (float*)smem;
  unsigned short* P_lds = (unsigned short*)(smem + 12800);
  float* Obuf = (float*)smem;
  float* msh = (float*)(smem + 32768);
  float* lsh = (float*)(smem + 32768 + 512);
  float* Lsh = (float*)(smem + 32768 + 1024);

  const int head = blockIdx.y;
  const int q0 = blockIdx.x * 32;
  const int tid = threadIdx.x, lane = tid & 63, wv = tid >> 6;
  const int r = lane & 15, g = lane >> 4;

  for (int idx = tid; idx < 32 * 96; idx += 256){
    int i = idx / 96, c = idx % 96;
    int token = head * NTOK + q0 + i;
    rel_s[i * 100 + c] = (c < 48) ? rel_h[(size_t)token * 48 + c]
                                  : rel_w[(size_t)token * 48 + (c - 48)];
  }
  __syncthreads();

  bf16x8 qf[2][2];
  #pragma unroll
  for (int mt = 0; mt < 2; mt++)
    #pragma unroll
    for (int ks = 0; ks < 2; ks++)
      qf[mt][ks] = *(const bf16x8*)&qg[((size_t)head * NTOK + q0 + mt * 16 + r) * 64 + ks * 32 + g * 8];

  f32x4 Oa[2][4];
  float mrun[2][4], lrun[2][4];
  #pragma unroll
  for (int mt = 0; mt < 2; mt++){
    #pragma unroll
    for (int dt = 0; dt < 4; dt++) Oa[mt][dt] = (f32x4){0.f, 0.f, 0.f, 0.f};
    #pragma unroll
    for (int reg = 0; reg < 4; reg++){ mrun[mt][reg] = -1e30f; lrun[mt][reg] = 0.f; }
  }

  unsigned short* pbase = &P_lds[wv * 32 * 72];
  const unsigned short* kbase = kg + (size_t)head * NTOK * 64;
  const unsigned short* vbase = vT + (size_t)head * 64 * NTOK;
  const int key_base = wv * 9 * 64;

  // preload K tile 0 (double-buffered across iterations)
  bf16x8 kc[4][2], kn[4][2];
  #pragma unroll
  for (int nt = 0; nt < 4; nt++)
    #pragma unroll
    for (int ks = 0; ks < 2; ks++)
      kc[nt][ks] = *(const bf16x8*)&kbase[(size_t)(key_base + nt * 16 + r) * 64 + ks * 32 + g * 8];

  for (int it = 0; it < 9; it++){
    int key0 = key_base + it * 64;

    // hoist V loads: issued now, consumed after softmax (latency hidden)
    bf16x8 vf[4][2];
    #pragma unroll
    for (int dt = 0; dt < 4; dt++)
      #pragma unroll
      for (int ks = 0; ks < 2; ks++)
        vf[dt][ks] = *(const bf16x8*)&vbase[(size_t)(dt * 16 + r) * NTOK + key0 + ks * 32 + g * 8];

    // prefetch next K tile
    if (it < 8){
      #pragma unroll
      for (int nt = 0; nt < 4; nt++)
        #pragma unroll
        for (int ks = 0; ks < 2; ks++)
          kn[nt][ks] = *(const bf16x8*)&kbase[(size_t)(key0 + 64 + nt * 16 + r) * 64 + ks * 32 + g * 8];
    }

    f32x4 s[2][4];
    #pragma unroll
    for (int mt = 0; mt < 2; mt++)
      #pragma unroll
      for (int nt = 0; nt < 4; nt++) s[mt][nt] = (f32x4){0.f, 0.f, 0.f, 0.f};
    #pragma unroll
    for (int mt = 0; mt < 2; mt++)
      #pragma unroll
      for (int nt = 0; nt < 4; nt++){
        s[mt][nt] = __builtin_amdgcn_mfma_f32_16x16x32_bf16(qf[mt][0], kc[nt][0], s[mt][nt], 0, 0, 0);
        s[mt][nt] = __builtin_amdgcn_mfma_f32_16x16x32_bf16(qf[mt][1], kc[nt][1], s[mt][nt], 0, 0, 0);
      }

    int kh[4], kw[4];
    #pragma unroll
    for (int nt = 0; nt < 4; nt++){
      int key = key0 + nt * 16 + r;
      kh[nt] = key / 48; kw[nt] = key % 48;
    }
    #pragma unroll
    for (int mt = 0; mt < 2; mt++)
      #pragma unroll
      for (int reg = 0; reg < 4; reg++){
        const float* rs = &rel_s[(mt * 16 + g * 4 + reg) * 100];
        #pragma unroll
        for (int nt = 0; nt < 4; nt++)
          s[mt][nt][reg] += rs[kh[nt]] + rs[48 + kw[nt]];
      }

    // online softmax (per-wave partial)
    #pragma unroll
    for (int mt = 0; mt < 2; mt++)
      #pragma unroll
      for (int reg = 0; reg < 4; reg++){
        float tm = fmaxf(fmaxf(s[mt][0][reg], s[mt][1][reg]), fmaxf(s[mt][2][reg], s[mt][3][reg]));
        tm = fmaxf(tm, __shfl_xor(tm, 1));
        tm = fmaxf(tm, __shfl_xor(tm, 2));
        tm = fmaxf(tm, __shfl_xor(tm, 4));
        tm = fmaxf(tm, __shfl_xor(tm, 8));
        float mold = mrun[mt][reg];
        float mnew = fmaxf(mold, tm);
        float alpha = __expf(mold - mnew);
        mrun[mt][reg] = mnew;
        float ps = 0.f;
        #pragma unroll
        for (int nt = 0; nt < 4; nt++){
          float p = __expf(s[mt][nt][reg] - mnew);
          s[mt][nt][reg] = p;
          ps += p;
        }
        ps += __shfl_xor(ps, 1);
        ps += __shfl_xor(ps, 2);
        ps += __shfl_xor(ps, 4);
        ps += __shfl_xor(ps, 8);
        lrun[mt][reg] = lrun[mt][reg] * alpha + ps;
        #pragma unroll
        for (int dt = 0; dt < 4; dt++) Oa[mt][dt][reg] *= alpha;
      }

    // P -> per-wave LDS (padded stride 72, D-layout write)
    #pragma unroll
    for (int mt = 0; mt < 2; mt++)
      #pragma unroll
      for (int reg = 0; reg < 4; reg++){
        int prow = mt * 16 + g * 4 + reg;
        #pragma unroll
        for (int nt = 0; nt < 4; nt++)
          pbase[prow * 72 + nt * 16 + r] = f2bf(s[mt][nt][reg]);
      }

    // P A-frag read + PV (vf loaded ~whole iteration ago)
    bf16x8 pf[2][2];
    #pragma unroll
    for (int mt = 0; mt < 2; mt++)
      #pragma unroll
      for (int ks = 0; ks < 2; ks++)
        pf[mt][ks] = *(const bf16x8*)&pbase[(mt * 16 + r) * 72 + ks * 32 + g * 8];
    #pragma unroll
    for (int dt = 0; dt < 4; dt++)
      #pragma unroll
      for (int ks = 0; ks < 2; ks++)
        #pragma unroll
        for (int mt = 0; mt < 2; mt++)
          Oa[mt][dt] = __builtin_amdgcn_mfma_f32_16x16x32_bf16(pf[mt][ks], vf[dt][ks], Oa[mt][dt], 0, 0, 0);

    // rotate K double-buffer
    if (it < 8){
      #pragma unroll
      for (int nt = 0; nt < 4; nt++)
        #pragma unroll
        for (int ks = 0; ks < 2; ks++)
          kc[nt][ks] = kn[nt][ks];
    }
  }

  // ---- cross-wave flash combine ----
  __syncthreads();   // all waves done with rel_s / P_lds
  if (r == 0){
    #pragma unroll
    for (int mt = 0; mt < 2; mt++)
      #pragma unroll
      for (int reg = 0; reg < 4; reg++){
        int row = mt * 16 + g * 4 + reg;
        msh[wv * 32 + row] = mrun[mt][reg];
        lsh[wv * 32 + row] = lrun[mt][reg];
      }
  }
  __syncthreads();
  #pragma unroll
  for (int mt = 0; mt < 2; mt++)
    #pragma unroll
    for (int reg = 0; reg < 4; reg++){
      int row = mt * 16 + g * 4 + reg;
      float m0v = msh[row], m1 = msh[32 + row], m2 = msh[64 + row], m3 = msh[96 + row];
      float M = fmaxf(fmaxf(m0v, m1), fmaxf(m2, m3));
      float L = lsh[row]      * __expf(m0v - M) + lsh[32 + row] * __expf(m1 - M)
              + lsh[64 + row] * __expf(m2 - M)  + lsh[96 + row] * __expf(m3 - M);
      float al = __expf(mrun[mt][reg] - M);
      if (wv == 0 && r == 0) Lsh[row] = L;
      #pragma unroll
      for (int dt = 0; dt < 4; dt++)
        Obuf[(wv * 32 + row) * 64 + dt * 16 + r] = Oa[mt][dt][reg] * al;
    }
  __syncthreads();
  {
    int row = tid >> 3;
    int dbase = (tid & 7) * 8;
    float sum[8];
    #pragma unroll
    for (int j = 0; j < 8; j++) sum[j] = 0.f;
    #pragma unroll
    for (int w4 = 0; w4 < 4; w4++){
      const float4* p = (const float4*)&Obuf[(w4 * 32 + row) * 64 + dbase];
      float4 a = p[0], b = p[1];
      sum[0] += a.x; sum[1] += a.y; sum[2] += a.z; sum[3] += a.w;
      sum[4] += b.x; sum[5] += b.y; sum[6] += b.z; sum[7] += b.w;
    }
    float invL = 1.f / Lsh[row];
    union { unsigned short u[8]; bf16x8 v; } o;
    #pragma unroll
    for (int j = 0; j < 8; j++) o.u[j] = f2bf(sum[j] * invL);
    int token = q0 + row;
    *(bf16x8*)&ao[(size_t)token * 768 + head * 64 + dbase] = o.v;
  }
}

// ---------------- proj GEMM ----------------
__global__ __launch_bounds__(256) void proj_gemm(
    const unsigned short* __restrict__ ag,   // [2304][768] bf16
    const unsigned short* __restrict__ wg,   // [768][768] bf16
    const float* __restrict__ bias,
    float* __restrict__ out)
{
  __shared__ short As[128*64];
  __shared__ short Bs[128*64];
  const int tid = threadIdx.x;
  const int lane = tid & 63;
  const int wv = tid >> 6;
  const int r = lane & 15, g = lane >> 4;
  const int wm = (wv >> 1) * 64, wn = (wv & 1) * 64;
  const int m0 = blockIdx.y * 128, n0 = blockIdx.x * 128;

  f32x4 acc[4][4];
  #pragma unroll
  for (int i = 0; i < 4; i++)
    #pragma unroll
    for (int j = 0; j < 4; j++) acc[i][j] = (f32x4){0.f, 0.f, 0.f, 0.f};

  for (int k0 = 0; k0 < 768; k0 += 64){
    __syncthreads();
    #pragma unroll
    for (int it = 0; it < 4; it++){
      int f = it * 256 + tid;
      int row = f >> 3, u = f & 7;
      int us = ((u ^ (row & 7)) << 3);
      gload_lds16(ag + (size_t)(m0 + row) * 768 + k0 + us, &As[f * 8]);
      gload_lds16(wg + (size_t)(n0 + row) * 768 + k0 + us, &Bs[f * 8]);
    }
    __syncthreads();
    #pragma unroll
    for (int ks = 0; ks < 2; ks++){
      bf16x8 af[4], bfr[4];
      #pragma unroll
      for (int mt = 0; mt < 4; mt++){
        int row = wm + mt * 16 + r;
        af[mt] = *(const bf16x8*)&As[row * 64 + ((((ks << 2) | g) ^ (r & 7)) << 3)];
      }
      #pragma unroll
      for (int nt = 0; nt < 4; nt++){
        int row = wn + nt * 16 + r;
        bfr[nt] = *(const bf16x8*)&Bs[row * 64 + ((((ks << 2) | g) ^ (r & 7)) << 3)];
      }
      #pragma unroll
      for (int mt = 0; mt < 4; mt++)
        #pragma unroll
        for (int nt = 0; nt < 4; nt++)
          acc[mt][nt] = __builtin_amdgcn_mfma_f32_16x16x32_bf16(af[mt], bfr[nt], acc[mt][nt], 0, 0, 0);
    }
  }

  #pragma unroll
  for (int mt = 0; mt < 4; mt++)
    #pragma unroll
    for (int reg = 0; reg < 4; reg++){
      int row_m = m0 + wm + mt * 16 + g * 4 + reg;
      #pragma unroll
      for (int nt = 0; nt < 4; nt++){
        int col = n0 + wn + nt * 16 + r;
        out[(size_t)row_m * 768 + col] = acc[mt][nt][reg] + bias[col];
      }
    }
}

extern "C" void kernel_launch(void* const* d_in, const int* in_sizes, int n_in,
                              void* d_out, int out_size, void* d_ws, size_t ws_size,
                              hipStream_t stream){
  (void)in_sizes; (void)n_in; (void)out_size; (void)ws_size;
  const float* x      = (const float*)d_in[0];
  const float* qkv_w  = (const float*)d_in[1];
  const float* qkv_b  = (const float*)d_in[2];
  const float* proj_w = (const float*)d_in[3];
  const float* proj_b = (const float*)d_in[4];
  const float* rph    = (const float*)d_in[5];
  const float* rpw    = (const float*)d_in[6];
  const float* Aq     = (const float*)d_in[7];
  const float* Bq     = (const float*)d_in[8];
  const float* Ak     = (const float*)d_in[9];
  const float* Bk     = (const float*)d_in[10];
  const float* Av     = (const float*)d_in[11];
  const float* Bv     = (const float*)d_in[12];

  char* w = (char*)d_ws;
  unsigned short* xb  = (unsigned short*)(w + 0);         // 2304*768 bf16
  unsigned short* wqb = (unsigned short*)(w + 3538944);   // 2304*768 bf16
  unsigned short* wpb = (unsigned short*)(w + 7077888);   //  768*768 bf16
  unsigned short* qb  = (unsigned short*)(w + 8257536);   // 12*2304*64 bf16 (scaled)
  unsigned short* kb  = (unsigned short*)(w + 11796480);  // 12*2304*64 bf16
  unsigned short* vtb = (unsigned short*)(w + 15335424);  // 12*64*2304 bf16
  float* tb           = (float*)(w + 18874368);           // 3*2304*4 f32
  float* rhb          = (float*)(w + 18984960);           // 12*2304*48 f32
  float* rwb          = (float*)(w + 24293376);           // 12*2304*48 f32
  unsigned short* aob = (unsigned short*)(w + 29601792);  // 2304*768 bf16

  cvt_f32_bf16<<<1728, 256, 0, stream>>>(x, xb, 442368);
  cvt_f32_bf16<<<1728, 256, 0, stream>>>(qkv_w, wqb, 442368);
  cvt_f32_bf16<<<576, 256, 0, stream>>>(proj_w, wpb, 147456);
  lora_t_kernel<<<576, 256, 0, stream>>>(x, Aq, Ak, Av, tb);
  qkv_gemm<<<dim3(18, 18), 256, 0, stream>>>(xb, wqb, qkv_b, tb, Bq, Bk, Bv, qb, kb, vtb);
  rel_kernel<<<dim3(48, 12), 256, 0, stream>>>(qb, rph, rpw, rhb, rwb);
  attn_kernel<<<dim3(72, 12), 256, 0, stream>>>(qb, kb, vtb, rhb, rwb, aob);
  proj_gemm<<<dim3(6, 18), 256, 0, stream>>>(aob, wpb, proj_b, (float*)d_out);
}

// Round 4
// 177.968 us; speedup vs baseline: 2.1381x; 1.5168x over previous
//
#include <hip/hip_runtime.h>

#define NTOK 2304   // 48*48 tokens
#define NH 12
#define HD 64

typedef __attribute__((ext_vector_type(8))) short bf16x8;
typedef __attribute__((ext_vector_type(4))) float f32x4;

__device__ __forceinline__ unsigned short f2bf(float f){
  union { float f; unsigned u; } v; v.f = f;
  unsigned r = v.u + 0x7fffu + ((v.u >> 16) & 1u);
  return (unsigned short)(r >> 16);
}
__device__ __forceinline__ float bf2f(unsigned short h){
  union { unsigned u; float f; } v; v.u = ((unsigned)h) << 16;
  return v.f;
}
__device__ __forceinline__ void gload_lds16(const void* g, void* lds){
  __builtin_amdgcn_global_load_lds(
    (const __attribute__((address_space(1))) unsigned int*)g,
    (__attribute__((address_space(3))) unsigned int*)lds, 16, 0, 0);
}

// ---------------- fp32 -> bf16 convert ----------------
__global__ __launch_bounds__(256) void cvt_f32_bf16(const float* __restrict__ src,
                                                    unsigned short* __restrict__ dst, int n4){
  int i = blockIdx.x * 256 + threadIdx.x;
  if (i >= n4) return;
  float4 v = ((const float4*)src)[i];
  union { unsigned short u[4]; unsigned long long ll; } o;
  o.u[0] = f2bf(v.x); o.u[1] = f2bf(v.y); o.u[2] = f2bf(v.z); o.u[3] = f2bf(v.w);
  ((unsigned long long*)dst)[i] = o.ll;
}

// ---------------- LoRA t = x @ A^T  (t[3][2304][4]) ----------------
__global__ __launch_bounds__(256) void lora_t_kernel(const float* __restrict__ x,
    const float* __restrict__ Aq, const float* __restrict__ Ak, const float* __restrict__ Av,
    float* __restrict__ t){
  int wave = (blockIdx.x * 256 + threadIdx.x) >> 6;   // token
  int lane = threadIdx.x & 63;
  if (wave >= NTOK) return;
  const float* xr = x + (size_t)wave * 768;
  float part[12];
  #pragma unroll
  for (int j = 0; j < 12; j++) part[j] = 0.f;
  for (int k = lane; k < 768; k += 64){
    float xv = xr[k];
    #pragma unroll
    for (int r = 0; r < 4; r++){
      part[r]     += xv * Aq[r*768 + k];
      part[4 + r] += xv * Ak[r*768 + k];
      part[8 + r] += xv * Av[r*768 + k];
    }
  }
  #pragma unroll
  for (int j = 0; j < 12; j++){
    float v = part[j];
    #pragma unroll
    for (int off = 32; off; off >>= 1) v += __shfl_xor(v, off);
    if (lane == 0){
      int mat = j >> 2, r = j & 3;
      t[((size_t)mat * NTOK + wave) * 4 + r] = v;
    }
  }
}

// ---------------- fused qkv GEMM (+bias +LoRA, writes q(scaled),k,vT) ----------------
__global__ __launch_bounds__(256) void qkv_gemm(
    const unsigned short* __restrict__ xg,   // [2304][768] bf16
    const unsigned short* __restrict__ wg,   // [2304][768] bf16
    const float* __restrict__ bias,          // [2304]
    const float* __restrict__ t,             // [3][2304][4]
    const float* __restrict__ Bq, const float* __restrict__ Bk, const float* __restrict__ Bv, // [768][4]
    unsigned short* __restrict__ qo,         // [12][2304][64]  (pre-scaled by 0.125)
    unsigned short* __restrict__ ko,         // [12][2304][64]
    unsigned short* __restrict__ vT)         // [12][64][2304]
{
  __shared__ short As[128*64];
  __shared__ short Bs[128*64];
  const int tid = threadIdx.x;
  const int lane = tid & 63;
  const int wv = tid >> 6;
  const int r = lane & 15, g = lane >> 4;
  const int wm = (wv >> 1) * 64, wn = (wv & 1) * 64;
  const int m0 = blockIdx.y * 128, n0 = blockIdx.x * 128;

  f32x4 acc[4][4];
  #pragma unroll
  for (int i = 0; i < 4; i++)
    #pragma unroll
    for (int j = 0; j < 4; j++) acc[i][j] = (f32x4){0.f, 0.f, 0.f, 0.f};

  for (int k0 = 0; k0 < 768; k0 += 64){
    __syncthreads();
    #pragma unroll
    for (int it = 0; it < 4; it++){
      int f = it * 256 + tid;
      int row = f >> 3, u = f & 7;
      int us = ((u ^ (row & 7)) << 3);
      gload_lds16(xg + (size_t)(m0 + row) * 768 + k0 + us, &As[f * 8]);
      gload_lds16(wg + (size_t)(n0 + row) * 768 + k0 + us, &Bs[f * 8]);
    }
    __syncthreads();
    #pragma unroll
    for (int ks = 0; ks < 2; ks++){
      bf16x8 af[4], bfr[4];
      #pragma unroll
      for (int mt = 0; mt < 4; mt++){
        int row = wm + mt * 16 + r;
        af[mt] = *(const bf16x8*)&As[row * 64 + ((((ks << 2) | g) ^ (r & 7)) << 3)];
      }
      #pragma unroll
      for (int nt = 0; nt < 4; nt++){
        int row = wn + nt * 16 + r;
        bfr[nt] = *(const bf16x8*)&Bs[row * 64 + ((((ks << 2) | g) ^ (r & 7)) << 3)];
      }
      #pragma unroll
      for (int mt = 0; mt < 4; mt++)
        #pragma unroll
        for (int nt = 0; nt < 4; nt++)
          acc[mt][nt] = __builtin_amdgcn_mfma_f32_16x16x32_bf16(af[mt], bfr[nt], acc[mt][nt], 0, 0, 0);
    }
  }

  const int part = n0 / 768;
  const float* Bl = (part == 0) ? Bq : ((part == 1) ? Bk : Bv);
  const float* tp = t + (size_t)part * NTOK * 4;
  #pragma unroll
  for (int mt = 0; mt < 4; mt++){
    #pragma unroll
    for (int reg = 0; reg < 4; reg++){
      int row_m = m0 + wm + mt * 16 + g * 4 + reg;
      float4 tv = *(const float4*)&tp[row_m * 4];
      #pragma unroll
      for (int nt = 0; nt < 4; nt++){
        int col = n0 + wn + nt * 16 + r;
        int cc = col - part * 768;
        float4 bw = *(const float4*)&Bl[cc * 4];
        float val = acc[mt][nt][reg] + bias[col]
                  + 0.25f * (tv.x * bw.x + tv.y * bw.y + tv.z * bw.z + tv.w * bw.w);
        int head = cc >> 6, d = cc & 63;
        if (part == 0)      qo[((size_t)head * NTOK + row_m) * 64 + d] = f2bf(val * 0.125f);
        else if (part == 1) ko[((size_t)head * NTOK + row_m) * 64 + d] = f2bf(val);
        else                vT[((size_t)head * 64 + d) * NTOK + row_m] = f2bf(val);
      }
    }
  }
}

// ---------------- rel_h / rel_w via MFMA ----------------
// Per (ih, head) block: G = Q_blk[48x64] @ [rph; rpw]^T [64x190], then gather:
//   rel_h[i][kh] = G[i][ih+47-kh] * 8,  rel_w[i][kw] = G[i][95 + i+47-kw] * 8
__global__ __launch_bounds__(256, 2) void rel_gemm(
    const unsigned short* __restrict__ qg,    // [12][2304][64] bf16 (scaled by 0.125)
    const unsigned short* __restrict__ rphb,  // [95][64] bf16
    const unsigned short* __restrict__ rpwb,  // [95][64] bf16
    float* __restrict__ rel_h,                // [12][2304][48]
    float* __restrict__ rel_w)                // [12][2304][48]
{
  __shared__ float G[48 * 196];
  const int ih = blockIdx.x, head = blockIdx.y;
  const int tid = threadIdx.x, lane = tid & 63, wv = tid >> 6;
  const int r = lane & 15, g = lane >> 4;
  const int q0 = ih * 48;

  // A fragments (3 M-tiles of 16 rows), straight from global
  bf16x8 af[3][2];
  #pragma unroll
  for (int mt = 0; mt < 3; mt++)
    #pragma unroll
    for (int ks = 0; ks < 2; ks++)
      af[mt][ks] = *(const bf16x8*)&qg[((size_t)head * NTOK + q0 + mt * 16 + r) * 64 + ks * 32 + g * 8];

  // B fragments: this wave's 3 N-tiles (cols wv*48 .. wv*48+47 of 192)
  bf16x8 bf[3][2];
  #pragma unroll
  for (int nt = 0; nt < 3; nt++){
    int col = wv * 48 + nt * 16 + r;
    const unsigned short* src = (col < 95) ? &rphb[(size_t)col * 64]
                              : (col < 190) ? &rpwb[(size_t)(col - 95) * 64]
                              : &rpwb[0];   // cols 190,191: garbage, never gathered
    #pragma unroll
    for (int ks = 0; ks < 2; ks++)
      bf[nt][ks] = *(const bf16x8*)&src[ks * 32 + g * 8];
  }

  f32x4 acc[3][3];
  #pragma unroll
  for (int mt = 0; mt < 3; mt++)
    #pragma unroll
    for (int nt = 0; nt < 3; nt++) acc[mt][nt] = (f32x4){0.f, 0.f, 0.f, 0.f};
  #pragma unroll
  for (int ks = 0; ks < 2; ks++)
    #pragma unroll
    for (int mt = 0; mt < 3; mt++)
      #pragma unroll
      for (int nt = 0; nt < 3; nt++)
        acc[mt][nt] = __builtin_amdgcn_mfma_f32_16x16x32_bf16(af[mt][ks], bf[nt][ks], acc[mt][nt], 0, 0, 0);

  // park G in LDS (stride 196 => non-pow2, conflicts <=2-way)
  #pragma unroll
  for (int mt = 0; mt < 3; mt++)
    #pragma unroll
    for (int reg = 0; reg < 4; reg++){
      int row = mt * 16 + g * 4 + reg;
      #pragma unroll
      for (int nt = 0; nt < 3; nt++)
        G[row * 196 + wv * 48 + nt * 16 + r] = acc[mt][nt][reg];
    }
  __syncthreads();

  // gather + *8 (undo q pre-scale) + store
  for (int idx = tid; idx < 48 * 96; idx += 256){
    int i = idx / 96, c = idx % 96;
    size_t gi = (size_t)head * NTOK + q0 + i;
    if (c < 48) rel_h[gi * 48 + c]        = G[i * 196 + (ih + 47 - c)] * 8.f;
    else        rel_w[gi * 48 + (c - 48)] = G[i * 196 + 95 + (i + 47 - (c - 48))] * 8.f;
  }
}

// ---------------- flash attention: 32 q-rows/block, 4 waves split KV ----------------
__global__ __launch_bounds__(256, 2) void attn_kernel(
    const unsigned short* __restrict__ qg,   // [12][2304][64] scaled
    const unsigned short* __restrict__ kg,   // [12][2304][64]
    const unsigned short* __restrict__ vT,   // [12][64][2304]
    const float* __restrict__ rel_h,         // [12][2304][48]
    const float* __restrict__ rel_w,         // [12][2304][48]
    unsigned short* __restrict__ ao)         // [2304][768]
{
  __shared__ __align__(16) char smem[32768 + 1152];
  float* rel_s = (float*)smem;
  unsigned short* P_lds = (unsigned short*)(smem + 12800);
  float* Obuf = (float*)smem;
  float* msh = (float*)(smem + 32768);
  float* lsh = (float*)(smem + 32768 + 512);
  float* Lsh = (float*)(smem + 32768 + 1024);

  const int head = blockIdx.y;
  const int q0 = blockIdx.x * 32;
  const int tid = threadIdx.x, lane = tid & 63, wv = tid >> 6;
  const int r = lane & 15, g = lane >> 4;

  for (int idx = tid; idx < 32 * 96; idx += 256){
    int i = idx / 96, c = idx % 96;
    int token = head * NTOK + q0 + i;
    rel_s[i * 100 + c] = (c < 48) ? rel_h[(size_t)token * 48 + c]
                                  : rel_w[(size_t)token * 48 + (c - 48)];
  }
  __syncthreads();

  bf16x8 qf[2][2];
  #pragma unroll
  for (int mt = 0; mt < 2; mt++)
    #pragma unroll
    for (int ks = 0; ks < 2; ks++)
      qf[mt][ks] = *(const bf16x8*)&qg[((size_t)head * NTOK + q0 + mt * 16 + r) * 64 + ks * 32 + g * 8];

  f32x4 Oa[2][4];
  float mrun[2][4], lrun[2][4];
  #pragma unroll
  for (int mt = 0; mt < 2; mt++){
    #pragma unroll
    for (int dt = 0; dt < 4; dt++) Oa[mt][dt] = (f32x4){0.f, 0.f, 0.f, 0.f};
    #pragma unroll
    for (int reg = 0; reg < 4; reg++){ mrun[mt][reg] = -1e30f; lrun[mt][reg] = 0.f; }
  }

  unsigned short* pbase = &P_lds[wv * 32 * 72];
  const unsigned short* kbase = kg + (size_t)head * NTOK * 64;
  const unsigned short* vbase = vT + (size_t)head * 64 * NTOK;
  const int key_base = wv * 9 * 64;

  bf16x8 kc[4][2], kn[4][2];
  #pragma unroll
  for (int nt = 0; nt < 4; nt++)
    #pragma unroll
    for (int ks = 0; ks < 2; ks++)
      kc[nt][ks] = *(const bf16x8*)&kbase[(size_t)(key_base + nt * 16 + r) * 64 + ks * 32 + g * 8];

  for (int it = 0; it < 9; it++){
    int key0 = key_base + it * 64;

    bf16x8 vf[4][2];
    #pragma unroll
    for (int dt = 0; dt < 4; dt++)
      #pragma unroll
      for (int ks = 0; ks < 2; ks++)
        vf[dt][ks] = *(const bf16x8*)&vbase[(size_t)(dt * 16 + r) * NTOK + key0 + ks * 32 + g * 8];

    if (it < 8){
      #pragma unroll
      for (int nt = 0; nt < 4; nt++)
        #pragma unroll
        for (int ks = 0; ks < 2; ks++)
          kn[nt][ks] = *(const bf16x8*)&kbase[(size_t)(key0 + 64 + nt * 16 + r) * 64 + ks * 32 + g * 8];
    }

    f32x4 s[2][4];
    #pragma unroll
    for (int mt = 0; mt < 2; mt++)
      #pragma unroll
      for (int nt = 0; nt < 4; nt++) s[mt][nt] = (f32x4){0.f, 0.f, 0.f, 0.f};
    #pragma unroll
    for (int mt = 0; mt < 2; mt++)
      #pragma unroll
      for (int nt = 0; nt < 4; nt++){
        s[mt][nt] = __builtin_amdgcn_mfma_f32_16x16x32_bf16(qf[mt][0], kc[nt][0], s[mt][nt], 0, 0, 0);
        s[mt][nt] = __builtin_amdgcn_mfma_f32_16x16x32_bf16(qf[mt][1], kc[nt][1], s[mt][nt], 0, 0, 0);
      }

    int kh[4], kw[4];
    #pragma unroll
    for (int nt = 0; nt < 4; nt++){
      int key = key0 + nt * 16 + r;
      kh[nt] = key / 48; kw[nt] = key % 48;
    }
    #pragma unroll
    for (int mt = 0; mt < 2; mt++)
      #pragma unroll
      for (int reg = 0; reg < 4; reg++){
        const float* rs = &rel_s[(mt * 16 + g * 4 + reg) * 100];
        #pragma unroll
        for (int nt = 0; nt < 4; nt++)
          s[mt][nt][reg] += rs[kh[nt]] + rs[48 + kw[nt]];
      }

    #pragma unroll
    for (int mt = 0; mt < 2; mt++)
      #pragma unroll
      for (int reg = 0; reg < 4; reg++){
        float tm = fmaxf(fmaxf(s[mt][0][reg], s[mt][1][reg]), fmaxf(s[mt][2][reg], s[mt][3][reg]));
        tm = fmaxf(tm, __shfl_xor(tm, 1));
        tm = fmaxf(tm, __shfl_xor(tm, 2));
        tm = fmaxf(tm, __shfl_xor(tm, 4));
        tm = fmaxf(tm, __shfl_xor(tm, 8));
        float mold = mrun[mt][reg];
        float mnew = fmaxf(mold, tm);
        float alpha = __expf(mold - mnew);
        mrun[mt][reg] = mnew;
        float ps = 0.f;
        #pragma unroll
        for (int nt = 0; nt < 4; nt++){
          float p = __expf(s[mt][nt][reg] - mnew);
          s[mt][nt][reg] = p;
          ps += p;
        }
        ps += __shfl_xor(ps, 1);
        ps += __shfl_xor(ps, 2);
        ps += __shfl_xor(ps, 4);
        ps += __shfl_xor(ps, 8);
        lrun[mt][reg] = lrun[mt][reg] * alpha + ps;
        #pragma unroll
        for (int dt = 0; dt < 4; dt++) Oa[mt][dt][reg] *= alpha;
      }

    #pragma unroll
    for (int mt = 0; mt < 2; mt++)
      #pragma unroll
      for (int reg = 0; reg < 4; reg++){
        int prow = mt * 16 + g * 4 + reg;
        #pragma unroll
        for (int nt = 0; nt < 4; nt++)
          pbase[prow * 72 + nt * 16 + r] = f2bf(s[mt][nt][reg]);
      }

    bf16x8 pf[2][2];
    #pragma unroll
    for (int mt = 0; mt < 2; mt++)
      #pragma unroll
      for (int ks = 0; ks < 2; ks++)
        pf[mt][ks] = *(const bf16x8*)&pbase[(mt * 16 + r) * 72 + ks * 32 + g * 8];
    #pragma unroll
    for (int dt = 0; dt < 4; dt++)
      #pragma unroll
      for (int ks = 0; ks < 2; ks++)
        #pragma unroll
        for (int mt = 0; mt < 2; mt++)
          Oa[mt][dt] = __builtin_amdgcn_mfma_f32_16x16x32_bf16(pf[mt][ks], vf[dt][ks], Oa[mt][dt], 0, 0, 0);

    if (it < 8){
      #pragma unroll
      for (int nt = 0; nt < 4; nt++)
        #pragma unroll
        for (int ks = 0; ks < 2; ks++)
          kc[nt][ks] = kn[nt][ks];
    }
  }

  __syncthreads();
  if (r == 0){
    #pragma unroll
    for (int mt = 0; mt < 2; mt++)
      #pragma unroll
      for (int reg = 0; reg < 4; reg++){
        int row = mt * 16 + g * 4 + reg;
        msh[wv * 32 + row] = mrun[mt][reg];
        lsh[wv * 32 + row] = lrun[mt][reg];
      }
  }
  __syncthreads();
  #pragma unroll
  for (int mt = 0; mt < 2; mt++)
    #pragma unroll
    for (int reg = 0; reg < 4; reg++){
      int row = mt * 16 + g * 4 + reg;
      float m0v = msh[row], m1 = msh[32 + row], m2 = msh[64 + row], m3 = msh[96 + row];
      float M = fmaxf(fmaxf(m0v, m1), fmaxf(m2, m3));
      float L = lsh[row]      * __expf(m0v - M) + lsh[32 + row] * __expf(m1 - M)
              + lsh[64 + row] * __expf(m2 - M)  + lsh[96 + row] * __expf(m3 - M);
      float al = __expf(mrun[mt][reg] - M);
      if (wv == 0 && r == 0) Lsh[row] = L;
      #pragma unroll
      for (int dt = 0; dt < 4; dt++)
        Obuf[(wv * 32 + row) * 64 + dt * 16 + r] = Oa[mt][dt][reg] * al;
    }
  __syncthreads();
  {
    int row = tid >> 3;
    int dbase = (tid & 7) * 8;
    float sum[8];
    #pragma unroll
    for (int j = 0; j < 8; j++) sum[j] = 0.f;
    #pragma unroll
    for (int w4 = 0; w4 < 4; w4++){
      const float4* p = (const float4*)&Obuf[(w4 * 32 + row) * 64 + dbase];
      float4 a = p[0], b = p[1];
      sum[0] += a.x; sum[1] += a.y; sum[2] += a.z; sum[3] += a.w;
      sum[4] += b.x; sum[5] += b.y; sum[6] += b.z; sum[7] += b.w;
    }
    float invL = 1.f / Lsh[row];
    union { unsigned short u[8]; bf16x8 v; } o;
    #pragma unroll
    for (int j = 0; j < 8; j++) o.u[j] = f2bf(sum[j] * invL);
    int token = q0 + row;
    *(bf16x8*)&ao[(size_t)token * 768 + head * 64 + dbase] = o.v;
  }
}

// ---------------- proj GEMM ----------------
__global__ __launch_bounds__(256) void proj_gemm(
    const unsigned short* __restrict__ ag,   // [2304][768] bf16
    const unsigned short* __restrict__ wg,   // [768][768] bf16
    const float* __restrict__ bias,
    float* __restrict__ out)
{
  __shared__ short As[128*64];
  __shared__ short Bs[128*64];
  const int tid = threadIdx.x;
  const int lane = tid & 63;
  const int wv = tid >> 6;
  const int r = lane & 15, g = lane >> 4;
  const int wm = (wv >> 1) * 64, wn = (wv & 1) * 64;
  const int m0 = blockIdx.y * 128, n0 = blockIdx.x * 128;

  f32x4 acc[4][4];
  #pragma unroll
  for (int i = 0; i < 4; i++)
    #pragma unroll
    for (int j = 0; j < 4; j++) acc[i][j] = (f32x4){0.f, 0.f, 0.f, 0.f};

  for (int k0 = 0; k0 < 768; k0 += 64){
    __syncthreads();
    #pragma unroll
    for (int it = 0; it < 4; it++){
      int f = it * 256 + tid;
      int row = f >> 3, u = f & 7;
      int us = ((u ^ (row & 7)) << 3);
      gload_lds16(ag + (size_t)(m0 + row) * 768 + k0 + us, &As[f * 8]);
      gload_lds16(wg + (size_t)(n0 + row) * 768 + k0 + us, &Bs[f * 8]);
    }
    __syncthreads();
    #pragma unroll
    for (int ks = 0; ks < 2; ks++){
      bf16x8 af[4], bfr[4];
      #pragma unroll
      for (int mt = 0; mt < 4; mt++){
        int row = wm + mt * 16 + r;
        af[mt] = *(const bf16x8*)&As[row * 64 + ((((ks << 2) | g) ^ (r & 7)) << 3)];
      }
      #pragma unroll
      for (int nt = 0; nt < 4; nt++){
        int row = wn + nt * 16 + r;
        bfr[nt] = *(const bf16x8*)&Bs[row * 64 + ((((ks << 2) | g) ^ (r & 7)) << 3)];
      }
      #pragma unroll
      for (int mt = 0; mt < 4; mt++)
        #pragma unroll
        for (int nt = 0; nt < 4; nt++)
          acc[mt][nt] = __builtin_amdgcn_mfma_f32_16x16x32_bf16(af[mt], bfr[nt], acc[mt][nt], 0, 0, 0);
    }
  }

  #pragma unroll
  for (int mt = 0; mt < 4; mt++)
    #pragma unroll
    for (int reg = 0; reg < 4; reg++){
      int row_m = m0 + wm + mt * 16 + g * 4 + reg;
      #pragma unroll
      for (int nt = 0; nt < 4; nt++){
        int col = n0 + wn + nt * 16 + r;
        out[(size_t)row_m * 768 + col] = acc[mt][nt][reg] + bias[col];
      }
    }
}

extern "C" void kernel_launch(void* const* d_in, const int* in_sizes, int n_in,
                              void* d_out, int out_size, void* d_ws, size_t ws_size,
                              hipStream_t stream){
  (void)in_sizes; (void)n_in; (void)out_size; (void)ws_size;
  const float* x      = (const float*)d_in[0];
  const float* qkv_w  = (const float*)d_in[1];
  const float* qkv_b  = (const float*)d_in[2];
  const float* proj_w = (const float*)d_in[3];
  const float* proj_b = (const float*)d_in[4];
  const float* rph    = (const float*)d_in[5];
  const float* rpw    = (const float*)d_in[6];
  const float* Aq     = (const float*)d_in[7];
  const float* Bq     = (const float*)d_in[8];
  const float* Ak     = (const float*)d_in[9];
  const float* Bk     = (const float*)d_in[10];
  const float* Av     = (const float*)d_in[11];
  const float* Bv     = (const float*)d_in[12];

  char* w = (char*)d_ws;
  unsigned short* xb  = (unsigned short*)(w + 0);         // 2304*768 bf16 (dead after qkv_gemm)
  unsigned short* wqb = (unsigned short*)(w + 3538944);   // 2304*768 bf16
  unsigned short* wpb = (unsigned short*)(w + 7077888);   //  768*768 bf16
  unsigned short* qb  = (unsigned short*)(w + 8257536);   // 12*2304*64 bf16 (scaled)
  unsigned short* kb  = (unsigned short*)(w + 11796480);  // 12*2304*64 bf16
  unsigned short* vtb = (unsigned short*)(w + 15335424);  // 12*64*2304 bf16
  float* tb           = (float*)(w + 18874368);           // 3*2304*4 f32
  float* rhb          = (float*)(w + 18984960);           // 12*2304*48 f32
  float* rwb          = (float*)(w + 24293376);           // 12*2304*48 f32
  unsigned short* aob = (unsigned short*)(w + 29601792);  // 2304*768 bf16
  // rph/rpw bf16 reuse the xb region (xb is dead once qkv_gemm has run)
  unsigned short* rphb = (unsigned short*)(w + 0);        // 95*64 bf16
  unsigned short* rpwb = (unsigned short*)(w + 12160);    // 95*64 bf16

  cvt_f32_bf16<<<1728, 256, 0, stream>>>(x, xb, 442368);
  cvt_f32_bf16<<<1728, 256, 0, stream>>>(qkv_w, wqb, 442368);
  cvt_f32_bf16<<<576, 256, 0, stream>>>(proj_w, wpb, 147456);
  lora_t_kernel<<<576, 256, 0, stream>>>(x, Aq, Ak, Av, tb);
  qkv_gemm<<<dim3(18, 18), 256, 0, stream>>>(xb, wqb, qkv_b, tb, Bq, Bk, Bv, qb, kb, vtb);
  cvt_f32_bf16<<<6, 256, 0, stream>>>(rph, rphb, 1520);   // after qkv_gemm: xb region now free
  cvt_f32_bf16<<<6, 256, 0, stream>>>(rpw, rpwb, 1520);
  rel_gemm<<<dim3(48, 12), 256, 0, stream>>>(qb, rphb, rpwb, rhb, rwb);
  attn_kernel<<<dim3(72, 12), 256, 0, stream>>>(qb, kb, vtb, rhb, rwb, aob);
  proj_gemm<<<dim3(6, 18), 256, 0, stream>>>(aob, wpb, proj_b, (float*)d_out);
}